// Round 1
// 222.163 us; speedup vs baseline: 1.1106x; 1.1106x over previous
//
#include <hip/hip_runtime.h>

#define NH 32
#define NKVH 8
#define HD 128
#define GRP 4
#define SCALE 0.08838834764831845f
#define LOG2E 1.4426950408889634f
#define PSTR 72
#define THR 8.0f

typedef __attribute__((ext_vector_type(8))) __bf16 bf16x8;
typedef __attribute__((ext_vector_type(4))) float f32x4;
typedef __attribute__((ext_vector_type(8))) unsigned short ushort8;

union U8 { ushort8 u; unsigned int d[4]; bf16x8 h; };

// packed RNE f32->bf16 pair (no builtin on gfx950; see T12 / m240)
__device__ inline unsigned int cvt_pk_bf16(float lo, float hi) {
  unsigned int r;
  asm("v_cvt_pk_bf16_f32 %0, %1, %2" : "=v"(r) : "v"(lo), "v"(hi));
  return r;
}

__device__ inline float fast_exp2(float x) {
#if __has_builtin(__builtin_amdgcn_exp2f)
  return __builtin_amdgcn_exp2f(x);
#else
  return exp2f(x);
#endif
}

__device__ inline float dpp_max16(float x) {
  x = fmaxf(x, __int_as_float(__builtin_amdgcn_mov_dpp(__float_as_int(x), 0xB1, 0xF, 0xF, true)));
  x = fmaxf(x, __int_as_float(__builtin_amdgcn_mov_dpp(__float_as_int(x), 0x4E, 0xF, 0xF, true)));
  x = fmaxf(x, __int_as_float(__builtin_amdgcn_mov_dpp(__float_as_int(x), 0x141, 0xF, 0xF, true)));
  x = fmaxf(x, __int_as_float(__builtin_amdgcn_mov_dpp(__float_as_int(x), 0x140, 0xF, 0xF, true)));
  return x;
}
__device__ inline float dpp_sum16(float x) {
  x += __int_as_float(__builtin_amdgcn_mov_dpp(__float_as_int(x), 0xB1, 0xF, 0xF, true));
  x += __int_as_float(__builtin_amdgcn_mov_dpp(__float_as_int(x), 0x4E, 0xF, 0xF, true));
  x += __int_as_float(__builtin_amdgcn_mov_dpp(__float_as_int(x), 0x141, 0xF, 0xF, true));
  x += __int_as_float(__builtin_amdgcn_mov_dpp(__float_as_int(x), 0x140, 0xF, 0xF, true));
  return x;
}

// global -> LDS direct DMA, 16B/lane. lds base wave-uniform; HW scatters lane*16.
__device__ inline void load_lds16(const unsigned short* g, unsigned short* l) {
  __builtin_amdgcn_global_load_lds((const __attribute__((address_space(1))) unsigned int*)g,
                                   (__attribute__((address_space(3))) unsigned int*)l, 16, 0, 0);
}

// ---------------- pre-pass: build packed bf16 K tiles + transposed V tiles ----------------
// K ws layout: [kvh][tile t][r=l&63][chunk c'=( (d>>3) ^ (r&7) )][e=d&7]   (unchanged)
// V ws layout: pi-permuted l-axis within each 64-row tile:  p = pi(l) = ((l&15)<<2)|(l>>4)
//   [kvh][tile t][d][chunk c'=( (p>>3) ^ (d&7) )][p&7]
// The SAME pi is applied to the P store in the attention kernel, so the PV contraction
// Sum_l P[q][l] V[l][d] is invariant; it lets a lane's 4 P values be memory-adjacent
// (one ds_write_b64 instead of 4 conflicting ds_write_b16).
__global__ __launch_bounds__(256) void prepass_kernel(
    const float* __restrict__ k, const float* __restrict__ v,
    const float* __restrict__ kc, const float* __restrict__ vc,
    const int* __restrict__ slots,
    unsigned short* __restrict__ Kws, unsigned short* __restrict__ Vws,
    int ctx, int L, int kblocks)
{
  if (blockIdx.x < (unsigned)kblocks) {
    // K: one thread per (kvh, l, 16-elem d-chunk)
    const int idx = blockIdx.x * 256 + threadIdx.x;
    const int L8  = L * 8;
    const int kvh = idx / L8;
    const int r2  = idx - kvh * L8;
    const int l   = r2 >> 3;
    const int c16 = idx & 7;
    const float* src = (l < ctx)
        ? kc + ((size_t)slots[l] * NKVH + kvh) * HD + c16 * 16
        : k + (size_t)(l - ctx) * (NKVH * HD) + kvh * HD + c16 * 16;
    float4 f[4];
#pragma unroll
    for (int i = 0; i < 4; ++i) f[i] = ((const float4*)src)[i];
    unsigned short* tile = Kws + (size_t)kvh * L * HD + (size_t)(l >> 6) * 8192;
    const int r = l & 63;
    const int c0 = (2 * c16) ^ (r & 7);
    const int c1 = (2 * c16 + 1) ^ (r & 7);
    U8 w0, w1;
    w0.d[0] = cvt_pk_bf16(f[0].x, f[0].y); w0.d[1] = cvt_pk_bf16(f[0].z, f[0].w);
    w0.d[2] = cvt_pk_bf16(f[1].x, f[1].y); w0.d[3] = cvt_pk_bf16(f[1].z, f[1].w);
    w1.d[0] = cvt_pk_bf16(f[2].x, f[2].y); w1.d[1] = cvt_pk_bf16(f[2].z, f[2].w);
    w1.d[2] = cvt_pk_bf16(f[3].x, f[3].y); w1.d[3] = cvt_pk_bf16(f[3].z, f[3].w);
    *(ushort8*)&tile[r * 128 + c0 * 8] = w0.u;
    *(ushort8*)&tile[r * 128 + c1 * 8] = w1.u;
  } else {
    // V: one thread per (kvh, d, 16-position p-chunk); lanes = consecutive d -> coalesced reads
    const int idx = (blockIdx.x - kblocks) * 256 + threadIdx.x;
    const int d   = idx & 127;
    const int t2  = idx >> 7;
    const int L16 = L >> 4;
    const int kvh = t2 / L16;
    const int lc  = t2 - kvh * L16;
    const int l0  = lc * 16;           // base of the 16 p-positions this thread fills
    const int lB  = l0 & ~63;          // tile base (in l)
    const int pc2 = (l0 >> 4) & 3;
    float vals[16];
#pragma unroll
    for (int j = 0; j < 16; ++j) {
      // p = (l0&63)+j  ->  l = lB + inv_pi(p) = lB + ((p&3)<<4) + (p>>2)
      const int l = lB + ((j & 3) << 4) + pc2 * 4 + (j >> 2);
      const float* sp = (l < ctx)
          ? vc + ((size_t)slots[l] * NKVH + kvh) * HD + d
          : v + (size_t)(l - ctx) * (NKVH * HD) + kvh * HD + d;
      vals[j] = *sp;
    }
    U8 w0, w1;
#pragma unroll
    for (int i = 0; i < 4; ++i) {
      w0.d[i] = cvt_pk_bf16(vals[2 * i],     vals[2 * i + 1]);
      w1.d[i] = cvt_pk_bf16(vals[8 + 2 * i], vals[9 + 2 * i]);
    }
    unsigned short* tile = Vws + (size_t)kvh * L * HD + (size_t)(l0 >> 6) * 8192;
    const int lt  = l0 & 63;
    const int cl0 = lt >> 3;
    *(ushort8*)&tile[d * 64 + ((cl0 ^ (d & 7)) * 8)] = w0.u;
    *(ushort8*)&tile[d * 64 + (((cl0 + 1) ^ (d & 7)) * 8)] = w1.u;
  }
}

// ---------------- main attention kernel ----------------
__global__ __launch_bounds__(256, 2) void attn_kernel(
    const float* __restrict__ q,
    const unsigned short* __restrict__ Kws, const unsigned short* __restrict__ Vws,
    float* __restrict__ out, int ctx, int L)
{
  __shared__ __align__(16) unsigned short Ks[2][8192];
  __shared__ __align__(16) unsigned short VTs[2][8192];
  __shared__ __align__(16) unsigned short Ps[4 * 16 * PSTR];

  const int bx   = blockIdx.x;
  const int kvh  = bx & 7;
  const int g    = (bx >> 3) & 3;
  const int qb   = bx >> 5;
  const int q0   = qb * 64;
  const int head = kvh * GRP + g;

  const int tid  = threadIdx.x;
  const int wave = tid >> 6;
  const int lane = tid & 63;
  const int col  = lane & 15;
  const int quad = lane >> 4;

  // Q fragments (A layout), pre-scaled by SCALE*log2(e) -> softmax runs in exp2 domain
  bf16x8 qf[4];
  {
    const float s2 = SCALE * LOG2E;
    const float* qp = q + (size_t)(q0 + wave * 16 + col) * (NH * HD) + head * HD;
#pragma unroll
    for (int kt = 0; kt < 4; ++kt) {
      const float4 a = *(const float4*)(qp + kt * 32 + quad * 8);
      const float4 b = *(const float4*)(qp + kt * 32 + quad * 8 + 4);
      U8 w;
      w.d[0] = cvt_pk_bf16(a.x * s2, a.y * s2);
      w.d[1] = cvt_pk_bf16(a.z * s2, a.w * s2);
      w.d[2] = cvt_pk_bf16(b.x * s2, b.y * s2);
      w.d[3] = cvt_pk_bf16(b.z * s2, b.w * s2);
      qf[kt] = w.h;
    }
  }

  f32x4 accO[8];
#pragma unroll
  for (int i = 0; i < 8; ++i) accO[i] = (f32x4){0.f, 0.f, 0.f, 0.f};
  float mrow = -1e30f;                  // shared running max per 4-row quad group
  float lrow[4] = {0.f, 0.f, 0.f, 0.f}; // per-lane partial row sums (reduced in epilogue)

  const int rowbase = q0 + wave * 16 + quad * 4;
  const size_t kvbase = (size_t)kvh * L * HD;
  const int n_tiles = (ctx + q0 + 64) >> 6;

  // DMA one 16KB K-tile + 16KB V-tile into buffer b. Wave w moves chunks 4w..4w+3 of each.
  auto dma_tile = [&](int t, int b) {
    const unsigned short* kg = Kws + kvbase + (size_t)t * 8192;
    const unsigned short* vg = Vws + kvbase + (size_t)t * 8192;
#pragma unroll
    for (int j = 0; j < 4; ++j) {
      const int ch = wave * 4 + j;                    // 1KB chunk (512 elems)
      load_lds16(kg + ch * 512 + lane * 8, &Ks[b][ch * 512]);
      load_lds16(vg + ch * 512 + lane * 8, &VTs[b][ch * 512]);
    }
  };

  dma_tile(0, 0);

  for (int it = 0; it < n_tiles; ++it) {
    __syncthreads();  // drains this tile's DMA (issued an iteration ago); frees buf^1

    if (it + 1 < n_tiles) dma_tile(it + 1, (it + 1) & 1);  // overlaps compute below

    const unsigned short* Kb = Ks[it & 1];
    const unsigned short* Vb = VTs[it & 1];
    const int kb = it << 6;

    // ---- S = Q K^T ----
    f32x4 S[4];
#pragma unroll
    for (int nt = 0; nt < 4; ++nt) S[nt] = (f32x4){0.f, 0.f, 0.f, 0.f};
#pragma unroll
    for (int kt = 0; kt < 4; ++kt)
#pragma unroll
      for (int nt = 0; nt < 4; ++nt) {
        const int row = nt * 16 + col;
        const bf16x8 kf = *(const bf16x8*)&Kb[row * 128 + (((kt * 4 + quad) ^ (row & 7)) << 3)];
        S[nt] = __builtin_amdgcn_mfma_f32_16x16x32_bf16(qf[kt], kf, S[nt], 0, 0, 0);
      }

    // ---- V fragment prefetch: issue reads now, latency hides under softmax VALU ----
    bf16x8 vf[8][2];
#pragma unroll
    for (int nt = 0; nt < 8; ++nt) {
      const int d = nt * 16 + col;
#pragma unroll
      for (int kt = 0; kt < 2; ++kt)
        vf[nt][kt] = *(const bf16x8*)&Vb[d * 64 + (((kt * 4 + quad) ^ (d & 7)) << 3)];
    }

    // ---- causal mask ----
    if (kb + 63 > ctx + q0 + wave * 16) {
#pragma unroll
      for (int r = 0; r < 4; ++r) {
        const int bound = ctx + rowbase + r;
#pragma unroll
        for (int nt = 0; nt < 4; ++nt) {
          const int l = kb + nt * 16 + col;
          if (l > bound) S[nt][r] = -1e30f;
        }
      }
    }

    // ---- online softmax (exp2 domain, shared per-quad max, deferred rescale) ----
    float M = fmaxf(fmaxf(S[0][0], S[0][1]), fmaxf(S[0][2], S[0][3]));
    M = fmaxf(M, fmaxf(fmaxf(S[1][0], S[1][1]), fmaxf(S[1][2], S[1][3])));
    M = fmaxf(M, fmaxf(fmaxf(S[2][0], S[2][1]), fmaxf(S[2][2], S[2][3])));
    M = fmaxf(M, fmaxf(fmaxf(S[3][0], S[3][1]), fmaxf(S[3][2], S[3][3])));
    M = dpp_max16(M);
    if (!__all(M - mrow <= THR)) {       // rare: ~once per block (first tile)
      const float mnew = fmaxf(mrow, M);
      const float a = fast_exp2(mrow - mnew);
      mrow = mnew;
#pragma unroll
      for (int r = 0; r < 4; ++r) lrow[r] *= a;
#pragma unroll
      for (int dd = 0; dd < 8; ++dd)
#pragma unroll
        for (int r = 0; r < 4; ++r) accO[dd][r] *= a;
    }
#pragma unroll
    for (int nt = 0; nt < 4; ++nt)
#pragma unroll
      for (int r = 0; r < 4; ++r) {
        const float p = fast_exp2(S[nt][r] - mrow);   // bounded by 2^THR
        S[nt][r] = p;
        lrow[r] += p;
      }

    // ---- P pack: pi-permuted store -> one ds_write_b64 per r (conflict-free) ----
    unsigned short* pw = &Ps[wave * 16 * PSTR];
#pragma unroll
    for (int r = 0; r < 4; ++r) {
      const unsigned long long lo = cvt_pk_bf16(S[0][r], S[1][r]);
      const unsigned long long hi = cvt_pk_bf16(S[2][r], S[3][r]);
      *(unsigned long long*)&pw[(quad * 4 + r) * PSTR + col * 4] = lo | (hi << 32);
    }
    asm volatile("s_waitcnt lgkmcnt(0)" ::: "memory");

    const bf16x8 pf0 = *(const bf16x8*)&pw[col * PSTR + quad * 8];
    const bf16x8 pf1 = *(const bf16x8*)&pw[col * PSTR + 32 + quad * 8];

    // ---- O += P V (V fragments already in registers) ----
#pragma unroll
    for (int nt = 0; nt < 8; ++nt) {
      accO[nt] = __builtin_amdgcn_mfma_f32_16x16x32_bf16(pf0, vf[nt][0], accO[nt], 0, 0, 0);
      accO[nt] = __builtin_amdgcn_mfma_f32_16x16x32_bf16(pf1, vf[nt][1], accO[nt], 0, 0, 0);
    }
  }

  // ---- epilogue: single row-sum reduction, then normalize ----
  float inv[4];
#pragma unroll
  for (int r = 0; r < 4; ++r) {
    lrow[r] = dpp_sum16(lrow[r]);
    inv[r] = 1.0f / lrow[r];
  }
  float* op = out + head * HD;
#pragma unroll
  for (int r = 0; r < 4; ++r) {
    float* orow = op + (size_t)(rowbase + r) * (NH * HD);
#pragma unroll
    for (int nt = 0; nt < 8; ++nt)
      orow[nt * 16 + col] = accO[nt][r] * inv[r];
  }
}

extern "C" void kernel_launch(void* const* d_in, const int* in_sizes, int n_in,
                              void* d_out, int out_size, void* d_ws, size_t ws_size,
                              hipStream_t stream) {
  const float* q  = (const float*)d_in[0];
  const float* k  = (const float*)d_in[1];
  const float* v  = (const float*)d_in[2];
  const float* kc = (const float*)d_in[3];
  const float* vc = (const float*)d_in[4];
  // d_in[5] slot_mapping: scatter targets disjoint from context_slots -> no output effect
  const int* ctx_slots = (const int*)d_in[6];
  float* out = (float*)d_out;

  const int seq = in_sizes[0] / (NH * HD);
  const int ctx = in_sizes[6];
  const int L   = ctx + seq;                 // 4096

  unsigned short* Kws = (unsigned short*)d_ws;              // NKVH*L*HD bf16 = 8.4MB
  unsigned short* Vws = Kws + (size_t)NKVH * L * HD;        // + 8.4MB (requires ws >= 16.8MB)

  const int kthreads = NKVH * L * (HD / 16);                // 262144
  const int vthreads = NKVH * (L / 16) * HD;                // 262144
  const int kblocks  = kthreads / 256;                      // 1024
  const int vblocks  = vthreads / 256;                      // 1024
  prepass_kernel<<<kblocks + vblocks, 256, 0, stream>>>(k, v, kc, vc, ctx_slots,
                                                        Kws, Vws, ctx, L, kblocks);

  const int nblocks = (seq / 64) * GRP * NKVH;              // 512
  attn_kernel<<<nblocks, 256, 0, stream>>>(q, Kws, Vws, out, ctx, L);
}

// Round 3
// 207.501 us; speedup vs baseline: 1.1891x; 1.0707x over previous
//
#include <hip/hip_runtime.h>

#define NH 32
#define NKVH 8
#define HD 128
#define GRP 4
#define SCALE 0.08838834764831845f
#define LOG2E 1.4426950408889634f
#define THR 8.0f

typedef __attribute__((ext_vector_type(8))) __bf16 bf16x8;
typedef __attribute__((ext_vector_type(4))) float f32x4;
typedef __attribute__((ext_vector_type(16))) float f32x16;
typedef __attribute__((ext_vector_type(8))) unsigned short ushort8;

union U8 { ushort8 u; unsigned int d[4]; bf16x8 h; };

// packed RNE f32->bf16 pair (no builtin on gfx950)
__device__ inline unsigned int cvt_pk_bf16(float lo, float hi) {
  unsigned int r;
  asm("v_cvt_pk_bf16_f32 %0, %1, %2" : "=v"(r) : "v"(lo), "v"(hi));
  return r;
}

__device__ inline float fast_exp2(float x) {
#if __has_builtin(__builtin_amdgcn_exp2f)
  return __builtin_amdgcn_exp2f(x);
#else
  return exp2f(x);
#endif
}

// global -> LDS direct DMA, 16B/lane. lds base wave-uniform; HW scatters lane*16.
__device__ inline void load_lds16(const unsigned short* g, unsigned short* l) {
  __builtin_amdgcn_global_load_lds((const __attribute__((address_space(1))) unsigned int*)g,
                                   (__attribute__((address_space(3))) unsigned int*)l, 16, 0, 0);
}

// ---------------- pre-pass: build packed bf16 K tiles + transposed V tiles ----------------
// K ws layout: [kvh][tile t][r=l&63][chunk c'=( (d>>3) ^ (r&7) )][e=d&7]
// V ws layout: [kvh][tile t][d][chunk c'=( ((l&63)>>3) ^ (d&7) )][l&7]   (natural l order)
__global__ __launch_bounds__(256) void prepass_kernel(
    const float* __restrict__ k, const float* __restrict__ v,
    const float* __restrict__ kc, const float* __restrict__ vc,
    const int* __restrict__ slots,
    unsigned short* __restrict__ Kws, unsigned short* __restrict__ Vws,
    int ctx, int L, int kblocks)
{
  if (blockIdx.x < (unsigned)kblocks) {
    // K: one thread per (kvh, l, 16-elem d-chunk)
    const int idx = blockIdx.x * 256 + threadIdx.x;
    const int L8  = L * 8;
    const int kvh = idx / L8;
    const int r2  = idx - kvh * L8;
    const int l   = r2 >> 3;
    const int c16 = idx & 7;
    const float* src = (l < ctx)
        ? kc + ((size_t)slots[l] * NKVH + kvh) * HD + c16 * 16
        : k + (size_t)(l - ctx) * (NKVH * HD) + kvh * HD + c16 * 16;
    float4 f[4];
#pragma unroll
    for (int i = 0; i < 4; ++i) f[i] = ((const float4*)src)[i];
    unsigned short* tile = Kws + (size_t)kvh * L * HD + (size_t)(l >> 6) * 8192;
    const int r = l & 63;
    const int c0 = (2 * c16) ^ (r & 7);
    const int c1 = (2 * c16 + 1) ^ (r & 7);
    U8 w0, w1;
    w0.d[0] = cvt_pk_bf16(f[0].x, f[0].y); w0.d[1] = cvt_pk_bf16(f[0].z, f[0].w);
    w0.d[2] = cvt_pk_bf16(f[1].x, f[1].y); w0.d[3] = cvt_pk_bf16(f[1].z, f[1].w);
    w1.d[0] = cvt_pk_bf16(f[2].x, f[2].y); w1.d[1] = cvt_pk_bf16(f[2].z, f[2].w);
    w1.d[2] = cvt_pk_bf16(f[3].x, f[3].y); w1.d[3] = cvt_pk_bf16(f[3].z, f[3].w);
    *(ushort8*)&tile[r * 128 + c0 * 8] = w0.u;
    *(ushort8*)&tile[r * 128 + c1 * 8] = w1.u;
  } else {
    // V: one thread per (kvh, d, 16-l chunk); lanes = consecutive d -> coalesced reads
    const int idx = (blockIdx.x - kblocks) * 256 + threadIdx.x;
    const int d   = idx & 127;
    const int t2  = idx >> 7;
    const int L16 = L >> 4;
    const int kvh = t2 / L16;
    const int lc  = t2 - kvh * L16;
    const int l0  = lc * 16;
    float vals[16];
#pragma unroll
    for (int i = 0; i < 16; ++i) {
      const int l = l0 + i;
      const float* sp = (l < ctx)
          ? vc + ((size_t)slots[l] * NKVH + kvh) * HD + d
          : v + (size_t)(l - ctx) * (NKVH * HD) + kvh * HD + d;
      vals[i] = *sp;
    }
    U8 w0, w1;
#pragma unroll
    for (int i = 0; i < 4; ++i) {
      w0.d[i] = cvt_pk_bf16(vals[2 * i],     vals[2 * i + 1]);
      w1.d[i] = cvt_pk_bf16(vals[8 + 2 * i], vals[9 + 2 * i]);
    }
    unsigned short* tile = Vws + (size_t)kvh * L * HD + (size_t)(l0 >> 6) * 8192;
    const int lt  = l0 & 63;
    const int cl0 = lt >> 3;
    *(ushort8*)&tile[d * 64 + ((cl0 ^ (d & 7)) * 8)] = w0.u;
    *(ushort8*)&tile[d * 64 + (((cl0 + 1) ^ (d & 7)) * 8)] = w1.u;
  }
}

// ---------------- main attention kernel ----------------
// Block: 512 threads = 8 waves = {kv-half group g2 (2)} x {head g (4)}.
// Wave owns 32 q-rows (q = q0 + lane&31) of head (kvh*4+g), over its kv half.
// S^T = mfma_32x32x16(K, Q): lane holds full P-row in regs -> in-register softmax.
// Cross-hi exchange via __shfl_xor(.,32) (direction-unambiguous; permlane32_swap
// direction was the round-2 correctness suspect).
// O^T = mfma_32x32x16(V^T, P^T). Halves merged through LDS at the end.
__global__ __launch_bounds__(512, 1) void attn_kernel(
    const float* __restrict__ q,
    const unsigned short* __restrict__ Kws, const unsigned short* __restrict__ Vws,
    float* __restrict__ out, int ctx, int L)
{
  __shared__ __align__(16) unsigned short lds[65536];  // 128KB: 2 groups x 2 bufs x (K 16KB | V 16KB)

  const int bx  = blockIdx.x;
  const int kvh = bx & 7;         // bx%8 == XCD id: all blocks of one kvh share an XCD's L2
  const int qb  = bx >> 3;
  const int q0  = qb * 32;

  const int tid  = threadIdx.x;
  const int wave = tid >> 6;
  const int lane = tid & 63;
  const int l31  = lane & 31;
  const int hi   = lane >> 5;
  const int g2   = wave >> 2;     // kv-half group
  const int g    = wave & 3;      // head within kv group
  const int head = kvh * GRP + g;
  const int swz  = (hi ^ (lane & 7)) << 3;   // LDS XOR-swizzle lane field (ushort units)

  // Q fragments (B-operand layout of 32x32x16): qf[ks] = Q[q0+l31][ks*16 + hi*8 + e] * SCALE*log2e
  bf16x8 qf[8];
  {
    const float s2 = SCALE * LOG2E;
    const float* qp = q + (size_t)(q0 + l31) * (NH * HD) + head * HD + hi * 8;
#pragma unroll
    for (int ks = 0; ks < 8; ++ks) {
      const float4 a = *(const float4*)(qp + ks * 16);
      const float4 b = *(const float4*)(qp + ks * 16 + 4);
      U8 w;
      w.d[0] = cvt_pk_bf16(a.x * s2, a.y * s2);
      w.d[1] = cvt_pk_bf16(a.z * s2, a.w * s2);
      w.d[2] = cvt_pk_bf16(b.x * s2, b.y * s2);
      w.d[3] = cvt_pk_bf16(b.z * s2, b.w * s2);
      qf[ks] = w.h;
    }
  }

  f32x16 accO[4];
#pragma unroll
  for (int i = 0; i < 4; ++i)
#pragma unroll
    for (int r = 0; r < 16; ++r) accO[i][r] = 0.f;
  float m = -1e30f;     // running max (pair-synced), exp2 domain
  float lrow = 0.f;     // per-lane partial row sum (this lane's l subset)

  const size_t kvbase = (size_t)kvh * L * HD;
  const unsigned short* Kg = Kws + kvbase;
  const unsigned short* Vg = Vws + kvbase;

  const int nt = (ctx + q0 + 95) >> 6;   // tiles covering l <= ctx+q0+31
  const int n0 = (nt + 1) >> 1;
  const int n1 = nt - n0;
  const int tbase = g2 ? n0 : 0;
  const int tcnt  = g2 ? n1 : n0;

  auto dma_tile = [&](int tg, int b) {
    unsigned short* Kt = &lds[(g2 * 2 + b) * 16384];
    unsigned short* Vt = Kt + 8192;
    const unsigned short* kg = Kg + (size_t)tg * 8192;
    const unsigned short* vg = Vg + (size_t)tg * 8192;
#pragma unroll
    for (int j = 0; j < 4; ++j) {
      const int ch = g * 4 + j;                 // 16 x 1KB chunks over the group's 4 waves
      load_lds16(kg + ch * 512 + lane * 8, &Kt[ch * 512]);
      load_lds16(vg + ch * 512 + lane * 8, &Vt[ch * 512]);
    }
  };

  dma_tile(tbase, 0);

  for (int j = 0; j < n0; ++j) {
    __syncthreads();   // drains DMA issued last iteration (vmcnt(0) before s_barrier)
    if (j + 1 < tcnt) dma_tile(tbase + j + 1, (j + 1) & 1);
    if (j < tcnt) {
      const int tg = tbase + j;
      const unsigned short* Kt = &lds[(g2 * 2 + (j & 1)) * 16384];
      const unsigned short* Vt = Kt + 8192;

      // ---- S^T = K Q^T : D[l][q], col(lane&31)=q, rows = l (C-layout regs) ----
      f32x16 S0, S1;
#pragma unroll
      for (int r = 0; r < 16; ++r) { S0[r] = 0.f; S1[r] = 0.f; }
      const int bk0 = l31 * 128 + swz;           // l-row mt0
      const int bk1 = bk0 + 4096;                // l-row mt1 (+32 rows)
      __builtin_amdgcn_s_setprio(1);
#pragma unroll
      for (int ks = 0; ks < 8; ++ks) {
        const bf16x8 k0 = *(const bf16x8*)&Kt[bk0 ^ (ks << 4)];
        const bf16x8 k1 = *(const bf16x8*)&Kt[bk1 ^ (ks << 4)];
        S0 = __builtin_amdgcn_mfma_f32_32x32x16_bf16(k0, qf[ks], S0, 0, 0, 0);
        S1 = __builtin_amdgcn_mfma_f32_32x32x16_bf16(k1, qf[ks], S1, 0, 0, 0);
      }
      __builtin_amdgcn_s_setprio(0);

      // ---- causal mask (diagonal always lives entirely in tile nt-1) ----
      const int kb = tg << 6;
      if (tg == nt - 1) {
        const int bound = ctx + q0 + l31;
#pragma unroll
        for (int r = 0; r < 16; ++r) {
          const int lof = (r & 3) + 8 * (r >> 2) + 4 * hi;
          if (kb + lof > bound)      S0[r] = -1e30f;
          if (kb + 32 + lof > bound) S1[r] = -1e30f;
        }
      }

      // ---- in-register online softmax (exp2 domain, deferred rescale) ----
      float t0 = fmaxf(fmaxf(S0[0], S0[1]), fmaxf(S0[2], S0[3]));
      float t1 = fmaxf(fmaxf(S0[4], S0[5]), fmaxf(S0[6], S0[7]));
      float t2 = fmaxf(fmaxf(S0[8], S0[9]), fmaxf(S0[10], S0[11]));
      float t3 = fmaxf(fmaxf(S0[12], S0[13]), fmaxf(S0[14], S0[15]));
      float u0 = fmaxf(fmaxf(S1[0], S1[1]), fmaxf(S1[2], S1[3]));
      float u1 = fmaxf(fmaxf(S1[4], S1[5]), fmaxf(S1[6], S1[7]));
      float u2 = fmaxf(fmaxf(S1[8], S1[9]), fmaxf(S1[10], S1[11]));
      float u3 = fmaxf(fmaxf(S1[12], S1[13]), fmaxf(S1[14], S1[15]));
      float M = fmaxf(fmaxf(fmaxf(t0, t1), fmaxf(t2, t3)),
                      fmaxf(fmaxf(u0, u1), fmaxf(u2, u3)));
      const float Mp = fmaxf(M, __shfl_xor(M, 32));   // row max across the lane pair
      if (!__all(Mp - m <= THR)) {          // rare
        const float mnew = fmaxf(m, Mp);
        const float a = fast_exp2(m - mnew);
        m = mnew;
        lrow *= a;
#pragma unroll
        for (int i = 0; i < 4; ++i)
#pragma unroll
          for (int r = 0; r < 16; ++r) accO[i][r] *= a;
      }
      float lr0 = 0.f, lr1 = 0.f;
#pragma unroll
      for (int r = 0; r < 16; ++r) {
        S0[r] = fast_exp2(S0[r] - m);
        S1[r] = fast_exp2(S1[r] - m);
        lr0 += S0[r];
        lr1 += S1[r];
      }
      lrow += lr0 + lr1;

      // ---- P^T B-fragments in-register via shfl_xor(32) (direction-agnostic) ----
      // Lane (l31,hi) holds P[q=l31][l = (r&3)+8*(r>>2)+4*hi (+32 for S1)].
      // B-fragment pfr[ks] needs l = ks*16 + 8*hi + e, e=0..7:
      //   hi=0 keeps own (A,B)=(l 0..3 blk) and needs partner's (A,B) (l 4..7 blk);
      //   hi=1 keeps own (C,D) and needs partner's (C,D).
      bf16x8 pfr[4];
#pragma unroll
      for (int h2 = 0; h2 < 2; ++h2) {
        {
          const unsigned int A = cvt_pk_bf16(S0[h2 * 8 + 0], S0[h2 * 8 + 1]);
          const unsigned int B = cvt_pk_bf16(S0[h2 * 8 + 2], S0[h2 * 8 + 3]);
          const unsigned int C = cvt_pk_bf16(S0[h2 * 8 + 4], S0[h2 * 8 + 5]);
          const unsigned int D = cvt_pk_bf16(S0[h2 * 8 + 6], S0[h2 * 8 + 7]);
          const unsigned int y1 = hi ? A : C;     // word my partner needs from me
          const unsigned int y2 = hi ? B : D;
          const unsigned int p1 = __shfl_xor(y1, 32);
          const unsigned int p2 = __shfl_xor(y2, 32);
          U8 w;
          w.d[0] = hi ? p1 : A;
          w.d[1] = hi ? p2 : B;
          w.d[2] = hi ? C : p1;
          w.d[3] = hi ? D : p2;
          pfr[h2] = w.h;
        }
        {
          const unsigned int A = cvt_pk_bf16(S1[h2 * 8 + 0], S1[h2 * 8 + 1]);
          const unsigned int B = cvt_pk_bf16(S1[h2 * 8 + 2], S1[h2 * 8 + 3]);
          const unsigned int C = cvt_pk_bf16(S1[h2 * 8 + 4], S1[h2 * 8 + 5]);
          const unsigned int D = cvt_pk_bf16(S1[h2 * 8 + 6], S1[h2 * 8 + 7]);
          const unsigned int y1 = hi ? A : C;
          const unsigned int y2 = hi ? B : D;
          const unsigned int p1 = __shfl_xor(y1, 32);
          const unsigned int p2 = __shfl_xor(y2, 32);
          U8 w;
          w.d[0] = hi ? p1 : A;
          w.d[1] = hi ? p2 : B;
          w.d[2] = hi ? C : p1;
          w.d[3] = hi ? D : p2;
          pfr[2 + h2] = w.h;
        }
      }

      // ---- O^T += V^T P^T : D[d][q] ----
      __builtin_amdgcn_s_setprio(1);
#pragma unroll
      for (int mdt = 0; mdt < 4; ++mdt) {
        const int bv = mdt * 2048 + l31 * 64 + swz;
#pragma unroll
        for (int ks = 0; ks < 4; ++ks) {
          const bf16x8 vf = *(const bf16x8*)&Vt[bv ^ (ks << 4)];
          accO[mdt] = __builtin_amdgcn_mfma_f32_32x32x16_bf16(vf, pfr[ks], accO[mdt], 0, 0, 0);
        }
      }
      __builtin_amdgcn_s_setprio(0);
    }
  }

  // ---- pair-combine row sum ----
  const float lsum = lrow + __shfl_xor(lrow, 32);   // full row sum for this half

  // ---- merge the two kv halves through LDS ----
  __syncthreads();                 // tile buffers dead; reuse LDS
  float* Om  = (float*)lds;        // [4 g][32 q][132]  (pad 132 to break bank alias)
  float* Mst = Om + 4 * 32 * 132;  // [4][32]
  float* Lst = Mst + 128;          // [4][32]
  float* orow = &Om[(g * 32 + l31) * 132];

  if (g2 == 1) {
#pragma unroll
    for (int mdt = 0; mdt < 4; ++mdt)
#pragma unroll
      for (int qd = 0; qd < 4; ++qd) {
        float4 w = { accO[mdt][qd * 4 + 0], accO[mdt][qd * 4 + 1],
                     accO[mdt][qd * 4 + 2], accO[mdt][qd * 4 + 3] };
        *(float4*)&orow[mdt * 32 + qd * 8 + hi * 4] = w;
      }
    if (hi == 0) { Mst[g * 32 + l31] = m; Lst[g * 32 + l31] = lsum; }
  }
  __syncthreads();
  if (g2 == 0) {
    const float m1 = Mst[g * 32 + l31];
    const float l1 = Lst[g * 32 + l31];
    const float mm = fmaxf(m, m1);
    const float a0 = fast_exp2(m - mm);
    const float a1 = fast_exp2(m1 - mm);
    const float inv = 1.0f / (lsum * a0 + l1 * a1);
    const float c0 = a0 * inv, c1 = a1 * inv;
#pragma unroll
    for (int mdt = 0; mdt < 4; ++mdt)
#pragma unroll
      for (int qd = 0; qd < 4; ++qd) {
        float4 w1 = *(float4*)&orow[mdt * 32 + qd * 8 + hi * 4];
        float4 w;
        w.x = accO[mdt][qd * 4 + 0] * c0 + w1.x * c1;
        w.y = accO[mdt][qd * 4 + 1] * c0 + w1.y * c1;
        w.z = accO[mdt][qd * 4 + 2] * c0 + w1.z * c1;
        w.w = accO[mdt][qd * 4 + 3] * c0 + w1.w * c1;
        *(float4*)&orow[mdt * 32 + qd * 8 + hi * 4] = w;
      }
  }
  __syncthreads();

  // ---- coalesced transposed store: thread -> (row-head rh, 32-d chunk) ----
  {
    const int rh = tid >> 2;                 // 0..127 = g*32 + q
    const int gg = rh >> 5, qq = rh & 31;
    const int dc = (tid & 3) * 32;
    const float* src = &Om[(gg * 32 + qq) * 132 + dc];
    float* dst = out + (size_t)(q0 + qq) * (NH * HD) + (kvh * GRP + gg) * HD + dc;
#pragma unroll
    for (int i = 0; i < 8; ++i)
      *(float4*)(dst + i * 4) = *(const float4*)(src + i * 4);
  }
}

extern "C" void kernel_launch(void* const* d_in, const int* in_sizes, int n_in,
                              void* d_out, int out_size, void* d_ws, size_t ws_size,
                              hipStream_t stream) {
  const float* q  = (const float*)d_in[0];
  const float* k  = (const float*)d_in[1];
  const float* v  = (const float*)d_in[2];
  const float* kc = (const float*)d_in[3];
  const float* vc = (const float*)d_in[4];
  // d_in[5] slot_mapping: scatter targets disjoint from context_slots -> no output effect
  const int* ctx_slots = (const int*)d_in[6];
  float* out = (float*)d_out;

  const int seq = in_sizes[0] / (NH * HD);
  const int ctx = in_sizes[6];
  const int L   = ctx + seq;                 // 4096

  unsigned short* Kws = (unsigned short*)d_ws;              // NKVH*L*HD bf16 = 8.4MB
  unsigned short* Vws = Kws + (size_t)NKVH * L * HD;        // + 8.4MB (requires ws >= 16.8MB)

  const int kthreads = NKVH * L * (HD / 16);                // 262144
  const int vthreads = NKVH * (L / 16) * HD;                // 262144
  const int kblocks  = kthreads / 256;                      // 1024
  const int vblocks  = vthreads / 256;                      // 1024
  prepass_kernel<<<kblocks + vblocks, 256, 0, stream>>>(k, v, kc, vc, ctx_slots,
                                                        Kws, Vws, ctx, L, kblocks);

  const int nblocks = (seq / 32) * NKVH;                    // 256
  attn_kernel<<<nblocks, 512, 0, stream>>>(q, Kws, Vws, out, ctx, L);
}